// Round 1
// baseline (614.729 us; speedup 1.0000x reference)
//
#include <hip/hip_runtime.h>
#include <hip/hip_bf16.h>
#include <math.h>

typedef __attribute__((ext_vector_type(4))) float f32x4;
typedef __attribute__((ext_vector_type(8))) short bf16x8;     // 8 bf16 in 4 VGPRs
typedef __attribute__((ext_vector_type(4))) unsigned short u16x4;
typedef __attribute__((ext_vector_type(8))) unsigned short u16x8;

__device__ __forceinline__ unsigned short f2b(float f) {
  unsigned int u = __builtin_bit_cast(unsigned int, f);
  u += 0x7fffu + ((u >> 16) & 1u);          // RNE
  return (unsigned short)(u >> 16);
}
__device__ __forceinline__ float b2f(unsigned short u) {
  unsigned int v = ((unsigned int)u) << 16;
  return __builtin_bit_cast(float, v);
}
__device__ __forceinline__ float gelu_exact(float x) {
  return 0.5f * x * (1.0f + erff(x * 0.70710678118654752440f));
}
__device__ __forceinline__ void gload_lds16(const void* g, void* l) {
  __builtin_amdgcn_global_load_lds((const __attribute__((address_space(1))) void*)g,
                                   (__attribute__((address_space(3))) void*)l,
                                   16, 0, 0);
}

// ---------------- x: f32 -> bf16 ----------------
__global__ void convert_x(const float* __restrict__ x, unsigned short* __restrict__ xb, int n4) {
  int stride = gridDim.x * blockDim.x;
  for (int i = blockIdx.x * blockDim.x + threadIdx.x; i < n4; i += stride) {
    f32x4 v = ((const f32x4*)x)[i];
    u16x4 o;
    o[0] = f2b(v[0]); o[1] = f2b(v[1]); o[2] = f2b(v[2]); o[3] = f2b(v[3]);
    ((u16x4*)xb)[i] = o;
  }
}

// ---------------- token MLPs: key/value tokens (bf16 out) ----------------
// key = gelu(tokens @ Wk1) @ Wk2 ; value = gelu(tokens @ Wv1) @ Wv2
// 16 tokens per block, 64 blocks.
__global__ void token_mlp(const float* __restrict__ tokens,
                          const float* __restrict__ Wk1, const float* __restrict__ Wk2,
                          const float* __restrict__ Wv1, const float* __restrict__ Wv2,
                          unsigned short* __restrict__ keyb, unsigned short* __restrict__ valb) {
  __shared__ float tok[16][64];
  __shared__ float hk[16][64];
  __shared__ float hv[16][64];
  const int tid = threadIdx.x;
  const int t0 = blockIdx.x * 16;
  for (int i = 0; i < 4; ++i) {
    int idx = i * 256 + tid;
    tok[idx >> 6][idx & 63] = tokens[(size_t)t0 * 64 + idx];
  }
  __syncthreads();
  {
    const int j = tid & 63;
    for (int ph = 0; ph < 4; ++ph) {
      int t = ph * 4 + (tid >> 6);
      float sk = 0.f, sv = 0.f;
      #pragma unroll 8
      for (int i = 0; i < 64; ++i) {
        float tv = tok[t][i];
        sk += tv * Wk1[i * 64 + j];
        sv += tv * Wv1[i * 64 + j];
      }
      hk[t][j] = gelu_exact(sk);
      hv[t][j] = gelu_exact(sv);
    }
  }
  __syncthreads();
  for (int p = 0; p < 8; ++p) {
    int c = p * 256 + tid;
    float ak[16] = {}, av[16] = {};
    for (int j = 0; j < 64; ++j) {
      float wk = Wk2[j * 2048 + c];
      float wv = Wv2[j * 2048 + c];
      #pragma unroll
      for (int t = 0; t < 16; ++t) { ak[t] += hk[t][j] * wk; av[t] += hv[t][j] * wv; }
    }
    #pragma unroll
    for (int t = 0; t < 16; ++t) {
      keyb[(size_t)(t0 + t) * 2048 + c] = f2b(ak[t]);
      valb[(size_t)(t0 + t) * 2048 + c] = f2b(av[t]);
    }
  }
}

// ---------------- value [1024,2048] -> Vt [2048,1024] ----------------
__global__ void transpose_v(const unsigned short* __restrict__ val,
                            unsigned short* __restrict__ vt) {
  __shared__ unsigned short t[64][66];
  const int f0 = blockIdx.x * 64, t0 = blockIdx.y * 64;
  const int tid = threadIdx.x;
  for (int i = 0; i < 16; ++i) {
    int idx = i * 256 + tid; int r = idx >> 6, c = idx & 63;
    t[r][c] = val[(size_t)(t0 + r) * 2048 + f0 + c];
  }
  __syncthreads();
  for (int i = 0; i < 16; ++i) {
    int idx = i * 256 + tid; int r = idx >> 6, c = idx & 63;
    vt[(size_t)(f0 + r) * 1024 + t0 + c] = t[c][r];
  }
}

// ---------------- GEMM: C[M,N] = A[M,K] @ B[N,K]^T, bf16 in, f32 acc ----------------
// 128x128 tile, BK=64, 4 waves (2x2), 16x16x32 MFMA, global_load_lds width 16.
template<int K, int N, int OUTB>
__global__ __launch_bounds__(256, 2)
void gemm_bt(const unsigned short* __restrict__ A, const unsigned short* __restrict__ B,
             void* __restrict__ Cptr) {
  __shared__ unsigned short sm[2 * 128 * 64];
  unsigned short* smA = sm;
  unsigned short* smB = sm + 128 * 64;
  const int tid  = threadIdx.x;
  const int wave = tid >> 6, lane = tid & 63;
  const int wr = wave >> 1, wc = wave & 1;
  const int m0 = blockIdx.y * 128, n0 = blockIdx.x * 128;

  const int ld_row_in_ch = lane >> 3;        // 0..7
  const int ld_col       = (lane & 7) * 8;   // 0,8,..,56

  f32x4 acc[4][4] = {};

  for (int k0 = 0; k0 < K; k0 += 64) {
    #pragma unroll
    for (int i = 0; i < 4; ++i) {
      int ch  = wave * 4 + i;                // 0..15, wave-uniform
      int row = ch * 8 + ld_row_in_ch;       // 0..127
      gload_lds16(A + (size_t)(m0 + row) * K + k0 + ld_col, smA + ch * 512);
      gload_lds16(B + (size_t)(n0 + row) * K + k0 + ld_col, smB + ch * 512);
    }
    __syncthreads();   // drains vmcnt before barrier

    #pragma unroll
    for (int kk = 0; kk < 2; ++kk) {
      bf16x8 af[4], bf[4];
      #pragma unroll
      for (int mi = 0; mi < 4; ++mi) {
        int row = wr * 64 + mi * 16 + (lane & 15);
        af[mi] = *(const bf16x8*)&smA[row * 64 + kk * 32 + (lane >> 4) * 8];
      }
      #pragma unroll
      for (int ni = 0; ni < 4; ++ni) {
        int row = wc * 64 + ni * 16 + (lane & 15);
        bf[ni] = *(const bf16x8*)&smB[row * 64 + kk * 32 + (lane >> 4) * 8];
      }
      #pragma unroll
      for (int mi = 0; mi < 4; ++mi)
        #pragma unroll
        for (int ni = 0; ni < 4; ++ni)
          acc[mi][ni] = __builtin_amdgcn_mfma_f32_16x16x32_bf16(af[mi], bf[ni], acc[mi][ni], 0, 0, 0);
    }
    __syncthreads();
  }

  const int cr = (lane >> 4) * 4;   // C/D: row = (lane>>4)*4 + reg
  const int cc = lane & 15;         //      col = lane&15
  if (OUTB) {
    unsigned short* C = (unsigned short*)Cptr;
    #pragma unroll
    for (int mi = 0; mi < 4; ++mi)
      #pragma unroll
      for (int ni = 0; ni < 4; ++ni) {
        int row = m0 + wr * 64 + mi * 16 + cr;
        int col = n0 + wc * 64 + ni * 16 + cc;
        #pragma unroll
        for (int r = 0; r < 4; ++r)
          C[(size_t)(row + r) * N + col] = f2b(acc[mi][ni][r]);
      }
  } else {
    float* C = (float*)Cptr;
    #pragma unroll
    for (int mi = 0; mi < 4; ++mi)
      #pragma unroll
      for (int ni = 0; ni < 4; ++ni) {
        int row = m0 + wr * 64 + mi * 16 + cr;
        int col = n0 + wc * 64 + ni * 16 + cc;
        #pragma unroll
        for (int r = 0; r < 4; ++r)
          C[(size_t)(row + r) * N + col] = acc[mi][ni][r];
      }
  }
}

// ---------------- row-wise RMS scale + gelu, in-place on bf16 sim ----------------
// weights = gelu(sim * sqrt(1024)/sqrt(sum(sim^2)))  ; one wave per row of 1024
__global__ void norm_gelu_rows(unsigned short* __restrict__ sim) {
  const int row  = blockIdx.x * 4 + (threadIdx.x >> 6);
  const int lane = threadIdx.x & 63;
  unsigned short* p = sim + (size_t)row * 1024;
  u16x8 v0 = *(const u16x8*)&p[lane * 8];
  u16x8 v1 = *(const u16x8*)&p[512 + lane * 8];
  float f0[8], f1[8];
  float s = 0.f;
  #pragma unroll
  for (int j = 0; j < 8; ++j) { f0[j] = b2f(v0[j]); s += f0[j] * f0[j]; }
  #pragma unroll
  for (int j = 0; j < 8; ++j) { f1[j] = b2f(v1[j]); s += f1[j] * f1[j]; }
  #pragma unroll
  for (int off = 32; off >= 1; off >>= 1) s += __shfl_xor(s, off, 64);
  float scale = 32.0f * rsqrtf(fmaxf(s, 1e-20f));
  u16x8 o0, o1;
  #pragma unroll
  for (int j = 0; j < 8; ++j) o0[j] = f2b(gelu_exact(f0[j] * scale));
  #pragma unroll
  for (int j = 0; j < 8; ++j) o1[j] = f2b(gelu_exact(f1[j] * scale));
  *(u16x8*)&p[lane * 8] = o0;
  *(u16x8*)&p[512 + lane * 8] = o1;
}

extern "C" void kernel_launch(void* const* d_in, const int* in_sizes, int n_in,
                              void* d_out, int out_size, void* d_ws, size_t ws_size,
                              hipStream_t stream) {
  const float* x      = (const float*)d_in[0];
  const float* tokens = (const float*)d_in[1];
  const float* Wk1    = (const float*)d_in[2];
  const float* Wk2    = (const float*)d_in[3];
  const float* Wv1    = (const float*)d_in[4];
  const float* Wv2    = (const float*)d_in[5];

  char* ws = (char*)d_ws;
  unsigned short* xb   = (unsigned short*)(ws);                              // 64 MB
  unsigned short* keyb = (unsigned short*)(ws + (size_t)64 * 1024 * 1024);   // 4 MB
  unsigned short* valb = (unsigned short*)(ws + (size_t)68 * 1024 * 1024);   // 4 MB
  unsigned short* vtb  = (unsigned short*)(ws + (size_t)72 * 1024 * 1024);   // 4 MB
  unsigned short* simb = (unsigned short*)(ws + (size_t)76 * 1024 * 1024);   // 32 MB

  hipLaunchKernelGGL(convert_x, dim3(2048), dim3(256), 0, stream, x, xb, 33554432 / 4);
  hipLaunchKernelGGL(token_mlp, dim3(64), dim3(256), 0, stream,
                     tokens, Wk1, Wk2, Wv1, Wv2, keyb, valb);
  hipLaunchKernelGGL(transpose_v, dim3(32, 16), dim3(256), 0, stream, valb, vtb);
  hipLaunchKernelGGL((gemm_bt<2048, 1024, 1>), dim3(8, 128), dim3(256), 0, stream,
                     xb, keyb, (void*)simb);
  hipLaunchKernelGGL(norm_gelu_rows, dim3(4096), dim3(256), 0, stream, simb);
  hipLaunchKernelGGL((gemm_bt<1024, 2048, 0>), dim3(16, 128), dim3(256), 0, stream,
                     simb, vtb, d_out);
}

// Round 2
// 287.969 us; speedup vs baseline: 2.1347x; 2.1347x over previous
//
#include <hip/hip_runtime.h>
#include <hip/hip_bf16.h>
#include <math.h>

typedef __attribute__((ext_vector_type(4))) float f32x4;
typedef __attribute__((ext_vector_type(8))) short bf16x8;     // 8 bf16 in 4 VGPRs
typedef __attribute__((ext_vector_type(4))) unsigned short u16x4;
typedef __attribute__((ext_vector_type(8))) unsigned short u16x8;

__device__ __forceinline__ unsigned short f2b(float f) {
  unsigned int u = __builtin_bit_cast(unsigned int, f);
  u += 0x7fffu + ((u >> 16) & 1u);          // RNE
  return (unsigned short)(u >> 16);
}
__device__ __forceinline__ float b2f(unsigned short u) {
  unsigned int v = ((unsigned int)u) << 16;
  return __builtin_bit_cast(float, v);
}
__device__ __forceinline__ float gelu_exact(float x) {
  return 0.5f * x * (1.0f + erff(x * 0.70710678118654752440f));
}
__device__ __forceinline__ void gload_lds16(const void* g, void* l) {
  __builtin_amdgcn_global_load_lds((const __attribute__((address_space(1))) void*)g,
                                   (__attribute__((address_space(3))) void*)l,
                                   16, 0, 0);
}

// ---------------- x: f32 -> bf16 ----------------
__global__ void convert_x(const float* __restrict__ x, unsigned short* __restrict__ xb, int n4) {
  int stride = gridDim.x * blockDim.x;
  for (int i = blockIdx.x * blockDim.x + threadIdx.x; i < n4; i += stride) {
    f32x4 v = ((const f32x4*)x)[i];
    u16x4 o;
    o[0] = f2b(v[0]); o[1] = f2b(v[1]); o[2] = f2b(v[2]); o[3] = f2b(v[3]);
    ((u16x4*)xb)[i] = o;
  }
}

// ---------------- token hidden: hk = gelu(tokens@Wk1), hv = gelu(tokens@Wv1) ----------------
// 4 tokens per block (tid>>6), one thread per (token, j). 256 blocks.
__global__ void token_h(const float* __restrict__ tokens,
                        const float* __restrict__ Wk1, const float* __restrict__ Wv1,
                        float* __restrict__ hk, float* __restrict__ hv) {
  __shared__ float tok[4][64];
  const int tid = threadIdx.x;
  const int tl = tid >> 6, j = tid & 63;
  const int t0 = blockIdx.x * 4;
  tok[tl][j] = tokens[(size_t)(t0 + tl) * 64 + j];
  __syncthreads();
  float sk = 0.f, sv = 0.f;
  #pragma unroll 16
  for (int i = 0; i < 64; ++i) {
    float tv = tok[tl][i];
    sk += tv * Wk1[i * 64 + j];
    sv += tv * Wv1[i * 64 + j];
  }
  hk[(size_t)(t0 + tl) * 64 + j] = gelu_exact(sk);
  hv[(size_t)(t0 + tl) * 64 + j] = gelu_exact(sv);
}

// ---------------- token proj: out[t,c] = sum_j h[t,j] * W2[j,c]  (bf16 out) ----------------
// grid (8 col-chunks, 64 token-groups, 2 {k,v}); 16 tokens x 256 cols per block.
__global__ void token_proj(const float* __restrict__ hk, const float* __restrict__ hv,
                           const float* __restrict__ Wk2, const float* __restrict__ Wv2,
                           unsigned short* __restrict__ keyb, unsigned short* __restrict__ valb) {
  const float* h  = blockIdx.z ? hv : hk;
  const float* W2 = blockIdx.z ? Wv2 : Wk2;
  unsigned short* out = blockIdx.z ? valb : keyb;
  __shared__ float sh[16][64];
  const int tid = threadIdx.x;
  const int c  = blockIdx.x * 256 + tid;
  const int t0 = blockIdx.y * 16;
  #pragma unroll
  for (int i = 0; i < 4; ++i) {
    int idx = i * 256 + tid;
    sh[idx >> 6][idx & 63] = h[(size_t)t0 * 64 + idx];
  }
  __syncthreads();
  float a[16] = {};
  #pragma unroll 8
  for (int j = 0; j < 64; ++j) {
    float w = W2[(size_t)j * 2048 + c];
    #pragma unroll
    for (int t = 0; t < 16; ++t) a[t] += sh[t][j] * w;
  }
  #pragma unroll
  for (int t = 0; t < 16; ++t)
    out[(size_t)(t0 + t) * 2048 + c] = f2b(a[t]);
}

// ---------------- value [1024,2048] -> Vt [2048,1024] ----------------
__global__ void transpose_v(const unsigned short* __restrict__ val,
                            unsigned short* __restrict__ vt) {
  __shared__ unsigned short t[64][66];
  const int f0 = blockIdx.x * 64, t0 = blockIdx.y * 64;
  const int tid = threadIdx.x;
  for (int i = 0; i < 16; ++i) {
    int idx = i * 256 + tid; int r = idx >> 6, c = idx & 63;
    t[r][c] = val[(size_t)(t0 + r) * 2048 + f0 + c];
  }
  __syncthreads();
  for (int i = 0; i < 16; ++i) {
    int idx = i * 256 + tid; int r = idx >> 6, c = idx & 63;
    vt[(size_t)(f0 + r) * 1024 + t0 + c] = t[c][r];
  }
}

// ---------------- GEMM: C[M,N] = A[M,K] @ B[N,K]^T, bf16 in, f32 acc ----------------
// 128x128 tile, BK=64, 4 waves (2x2), 16x16x32 MFMA, global_load_lds width 16.
template<int K, int N, int OUTB>
__global__ __launch_bounds__(256, 2)
void gemm_bt(const unsigned short* __restrict__ A, const unsigned short* __restrict__ B,
             void* __restrict__ Cptr) {
  __shared__ unsigned short sm[2 * 128 * 64];
  unsigned short* smA = sm;
  unsigned short* smB = sm + 128 * 64;
  const int tid  = threadIdx.x;
  const int wave = tid >> 6, lane = tid & 63;
  const int wr = wave >> 1, wc = wave & 1;
  const int m0 = blockIdx.y * 128, n0 = blockIdx.x * 128;

  const int ld_row_in_ch = lane >> 3;        // 0..7
  const int ld_col       = (lane & 7) * 8;   // 0,8,..,56

  f32x4 acc[4][4] = {};

  for (int k0 = 0; k0 < K; k0 += 64) {
    #pragma unroll
    for (int i = 0; i < 4; ++i) {
      int ch  = wave * 4 + i;                // 0..15, wave-uniform
      int row = ch * 8 + ld_row_in_ch;       // 0..127
      gload_lds16(A + (size_t)(m0 + row) * K + k0 + ld_col, smA + ch * 512);
      gload_lds16(B + (size_t)(n0 + row) * K + k0 + ld_col, smB + ch * 512);
    }
    __syncthreads();   // drains vmcnt before barrier

    #pragma unroll
    for (int kk = 0; kk < 2; ++kk) {
      bf16x8 af[4], bf[4];
      #pragma unroll
      for (int mi = 0; mi < 4; ++mi) {
        int row = wr * 64 + mi * 16 + (lane & 15);
        af[mi] = *(const bf16x8*)&smA[row * 64 + kk * 32 + (lane >> 4) * 8];
      }
      #pragma unroll
      for (int ni = 0; ni < 4; ++ni) {
        int row = wc * 64 + ni * 16 + (lane & 15);
        bf[ni] = *(const bf16x8*)&smB[row * 64 + kk * 32 + (lane >> 4) * 8];
      }
      #pragma unroll
      for (int mi = 0; mi < 4; ++mi)
        #pragma unroll
        for (int ni = 0; ni < 4; ++ni)
          acc[mi][ni] = __builtin_amdgcn_mfma_f32_16x16x32_bf16(af[mi], bf[ni], acc[mi][ni], 0, 0, 0);
    }
    __syncthreads();
  }

  const int cr = (lane >> 4) * 4;   // C/D: row = (lane>>4)*4 + reg
  const int cc = lane & 15;         //      col = lane&15
  if (OUTB) {
    unsigned short* C = (unsigned short*)Cptr;
    #pragma unroll
    for (int mi = 0; mi < 4; ++mi)
      #pragma unroll
      for (int ni = 0; ni < 4; ++ni) {
        int row = m0 + wr * 64 + mi * 16 + cr;
        int col = n0 + wc * 64 + ni * 16 + cc;
        #pragma unroll
        for (int r = 0; r < 4; ++r)
          C[(size_t)(row + r) * N + col] = f2b(acc[mi][ni][r]);
      }
  } else {
    float* C = (float*)Cptr;
    #pragma unroll
    for (int mi = 0; mi < 4; ++mi)
      #pragma unroll
      for (int ni = 0; ni < 4; ++ni) {
        int row = m0 + wr * 64 + mi * 16 + cr;
        int col = n0 + wc * 64 + ni * 16 + cc;
        #pragma unroll
        for (int r = 0; r < 4; ++r)
          C[(size_t)(row + r) * N + col] = acc[mi][ni][r];
      }
  }
}

// ---------------- row-wise RMS scale + gelu, in-place on bf16 sim ----------------
// weights = gelu(sim * sqrt(1024)/sqrt(sum(sim^2)))  ; one wave per row of 1024
__global__ void norm_gelu_rows(unsigned short* __restrict__ sim) {
  const int row  = blockIdx.x * 4 + (threadIdx.x >> 6);
  const int lane = threadIdx.x & 63;
  unsigned short* p = sim + (size_t)row * 1024;
  u16x8 v0 = *(const u16x8*)&p[lane * 8];
  u16x8 v1 = *(const u16x8*)&p[512 + lane * 8];
  float f0[8], f1[8];
  float s = 0.f;
  #pragma unroll
  for (int j = 0; j < 8; ++j) { f0[j] = b2f(v0[j]); s += f0[j] * f0[j]; }
  #pragma unroll
  for (int j = 0; j < 8; ++j) { f1[j] = b2f(v1[j]); s += f1[j] * f1[j]; }
  #pragma unroll
  for (int off = 32; off >= 1; off >>= 1) s += __shfl_xor(s, off, 64);
  float scale = 32.0f * rsqrtf(fmaxf(s, 1e-20f));
  u16x8 o0, o1;
  #pragma unroll
  for (int j = 0; j < 8; ++j) o0[j] = f2b(gelu_exact(f0[j] * scale));
  #pragma unroll
  for (int j = 0; j < 8; ++j) o1[j] = f2b(gelu_exact(f1[j] * scale));
  *(u16x8*)&p[lane * 8] = o0;
  *(u16x8*)&p[512 + lane * 8] = o1;
}

extern "C" void kernel_launch(void* const* d_in, const int* in_sizes, int n_in,
                              void* d_out, int out_size, void* d_ws, size_t ws_size,
                              hipStream_t stream) {
  const float* x      = (const float*)d_in[0];
  const float* tokens = (const float*)d_in[1];
  const float* Wk1    = (const float*)d_in[2];
  const float* Wk2    = (const float*)d_in[3];
  const float* Wv1    = (const float*)d_in[4];
  const float* Wv2    = (const float*)d_in[5];

  char* ws = (char*)d_ws;
  unsigned short* xb   = (unsigned short*)(ws);                              // 64 MB
  unsigned short* keyb = (unsigned short*)(ws + (size_t)64 * 1024 * 1024);   // 4 MB
  unsigned short* valb = (unsigned short*)(ws + (size_t)68 * 1024 * 1024);   // 4 MB
  unsigned short* vtb  = (unsigned short*)(ws + (size_t)72 * 1024 * 1024);   // 4 MB
  unsigned short* simb = (unsigned short*)(ws + (size_t)76 * 1024 * 1024);   // 32 MB
  // hk/hv (256 KB each) alias the simb region: dead before gemm1 writes simb.
  float* hk = (float*)(ws + (size_t)76 * 1024 * 1024);
  float* hv = (float*)(ws + (size_t)77 * 1024 * 1024);

  hipLaunchKernelGGL(convert_x, dim3(2048), dim3(256), 0, stream, x, xb, 33554432 / 4);
  hipLaunchKernelGGL(token_h, dim3(256), dim3(256), 0, stream, tokens, Wk1, Wv1, hk, hv);
  hipLaunchKernelGGL(token_proj, dim3(8, 64, 2), dim3(256), 0, stream,
                     hk, hv, Wk2, Wv2, keyb, valb);
  hipLaunchKernelGGL(transpose_v, dim3(32, 16), dim3(256), 0, stream, valb, vtb);
  hipLaunchKernelGGL((gemm_bt<2048, 1024, 1>), dim3(8, 128), dim3(256), 0, stream,
                     xb, keyb, (void*)simb);
  hipLaunchKernelGGL(norm_gelu_rows, dim3(4096), dim3(256), 0, stream, simb);
  hipLaunchKernelGGL((gemm_bt<1024, 2048, 0>), dim3(16, 128), dim3(256), 0, stream,
                     simb, vtb, d_out);
}

// Round 3
// 229.929 us; speedup vs baseline: 2.6736x; 1.2524x over previous
//
#include <hip/hip_runtime.h>
#include <hip/hip_bf16.h>
#include <math.h>

typedef __attribute__((ext_vector_type(4))) float f32x4;
typedef __attribute__((ext_vector_type(8))) short bf16x8;     // 8 bf16 in 4 VGPRs
typedef __attribute__((ext_vector_type(4))) unsigned short u16x4;
typedef __attribute__((ext_vector_type(8))) unsigned short u16x8;

__device__ __forceinline__ unsigned short f2b(float f) {
  unsigned int u = __builtin_bit_cast(unsigned int, f);
  u += 0x7fffu + ((u >> 16) & 1u);          // RNE
  return (unsigned short)(u >> 16);
}
__device__ __forceinline__ float b2f(unsigned short u) {
  unsigned int v = ((unsigned int)u) << 16;
  return __builtin_bit_cast(float, v);
}
__device__ __forceinline__ float gelu_exact(float x) {
  return 0.5f * x * (1.0f + erff(x * 0.70710678118654752440f));
}
__device__ __forceinline__ void gload_lds16(const void* g, void* l) {
  __builtin_amdgcn_global_load_lds((const __attribute__((address_space(1))) void*)g,
                                   (__attribute__((address_space(3))) void*)l,
                                   16, 0, 0);
}

// ---------------- x: f32 -> bf16 ----------------
__global__ void convert_x(const float* __restrict__ x, unsigned short* __restrict__ xb, int n4) {
  int stride = gridDim.x * blockDim.x;
  for (int i = blockIdx.x * blockDim.x + threadIdx.x; i < n4; i += stride) {
    f32x4 v = ((const f32x4*)x)[i];
    u16x4 o;
    o[0] = f2b(v[0]); o[1] = f2b(v[1]); o[2] = f2b(v[2]); o[3] = f2b(v[3]);
    ((u16x4*)xb)[i] = o;
  }
}

// ---------------- token hidden: hk = gelu(tokens@Wk1), hv = gelu(tokens@Wv1) ----------------
__global__ void token_h(const float* __restrict__ tokens,
                        const float* __restrict__ Wk1, const float* __restrict__ Wv1,
                        float* __restrict__ hk, float* __restrict__ hv) {
  __shared__ float tok[4][64];
  const int tid = threadIdx.x;
  const int tl = tid >> 6, j = tid & 63;
  const int t0 = blockIdx.x * 4;
  tok[tl][j] = tokens[(size_t)(t0 + tl) * 64 + j];
  __syncthreads();
  float sk = 0.f, sv = 0.f;
  #pragma unroll 16
  for (int i = 0; i < 64; ++i) {
    float tv = tok[tl][i];
    sk += tv * Wk1[i * 64 + j];
    sv += tv * Wv1[i * 64 + j];
  }
  hk[(size_t)(t0 + tl) * 64 + j] = gelu_exact(sk);
  hv[(size_t)(t0 + tl) * 64 + j] = gelu_exact(sv);
}

// ---------------- token proj: out[t,c] = sum_j h[t,j] * W2[j,c]  (bf16 out) ----------------
__global__ void token_proj(const float* __restrict__ hk, const float* __restrict__ hv,
                           const float* __restrict__ Wk2, const float* __restrict__ Wv2,
                           unsigned short* __restrict__ keyb, unsigned short* __restrict__ valb) {
  const float* h  = blockIdx.z ? hv : hk;
  const float* W2 = blockIdx.z ? Wv2 : Wk2;
  unsigned short* out = blockIdx.z ? valb : keyb;
  __shared__ float sh[16][64];
  const int tid = threadIdx.x;
  const int c  = blockIdx.x * 256 + tid;
  const int t0 = blockIdx.y * 16;
  #pragma unroll
  for (int i = 0; i < 4; ++i) {
    int idx = i * 256 + tid;
    sh[idx >> 6][idx & 63] = h[(size_t)t0 * 64 + idx];
  }
  __syncthreads();
  float a[16] = {};
  #pragma unroll 8
  for (int j = 0; j < 64; ++j) {
    float w = W2[(size_t)j * 2048 + c];
    #pragma unroll
    for (int t = 0; t < 16; ++t) a[t] += sh[t][j] * w;
  }
  #pragma unroll
  for (int t = 0; t < 16; ++t)
    out[(size_t)(t0 + t) * 2048 + c] = f2b(a[t]);
}

// ---------------- value [1024,2048] -> Vt [2048,1024] ----------------
__global__ void transpose_v(const unsigned short* __restrict__ val,
                            unsigned short* __restrict__ vt) {
  __shared__ unsigned short t[64][66];
  const int f0 = blockIdx.x * 64, t0 = blockIdx.y * 64;
  const int tid = threadIdx.x;
  for (int i = 0; i < 16; ++i) {
    int idx = i * 256 + tid; int r = idx >> 6, c = idx & 63;
    t[r][c] = val[(size_t)(t0 + r) * 2048 + f0 + c];
  }
  __syncthreads();
  for (int i = 0; i < 16; ++i) {
    int idx = i * 256 + tid; int r = idx >> 6, c = idx & 63;
    vt[(size_t)(f0 + r) * 1024 + t0 + c] = t[c][r];
  }
}

// ---------------- staging: one 256x64 bf16 tile, T2-swizzled via global source ----------------
// LDS linear dest (gload_lds requirement); global col16 pre-XORed so that
// LDS(row, c16) holds global(row, c16 ^ (row&7)).  4 loads/thread @ 512 threads.
template<int LDK>
__device__ __forceinline__ void stage_tile(const unsigned short* __restrict__ g,
                                           int row0, int k0, unsigned short* lds,
                                           int tid, int wave) {
  #pragma unroll
  for (int j = 0; j < 4; ++j) {
    int lin = j * 512 + tid;
    int row = lin >> 3;                       // 0..255
    int c16 = (lin & 7) ^ (row & 7);          // pre-swizzled source column (16B units)
    gload_lds16(g + (size_t)(row0 + row) * LDK + k0 + c16 * 8,
                lds + (size_t)(j * 512 + wave * 64) * 8);
  }
}

// ---------------- GEMM: C[M,N] = A[M,K] @ B[N,K]^T, bf16 in, f32 acc ----------------
// 256x256 tile, BK=64, 8 waves (2Mx4N), dbuf LDS 128KB, 4-phase counted-vmcnt schedule.
// T1 XCD swizzle + T2 LDS swizzle + T3/T4 phases + T5 setprio.
template<int K, int N, int OUTB>
__global__ __launch_bounds__(512, 2)
void gemm256(const unsigned short* __restrict__ A, const unsigned short* __restrict__ B,
             void* __restrict__ Cptr) {
  __shared__ unsigned short sm[65536];        // [buf][A|B][256][64]  = 128 KB
  const int tid  = threadIdx.x;
  const int wave = tid >> 6, lane = tid & 63;
  const int wm = wave >> 2, wn = wave & 3;    // 2 x 4 wave grid
  const int lrow = lane & 15, q = lane >> 4;  // fragment row / 8-elem quarter

  // T1: bijective XCD swizzle (nwg % 8 == 0): XCD x owns an 8-wide m-strip, all n.
  const int per = gridDim.x >> 3;
  const int swz = (blockIdx.x & 7) * per + (blockIdx.x >> 3);
  constexpr int NT = N >> 8;
  const int m0 = (swz / NT) << 8, n0 = (swz % NT) << 8;

  constexpr int NS = K >> 6;                  // K-steps

  // prologue: stage tile 0 into buf0
  stage_tile<K>(A, m0, 0, sm,         tid, wave);
  stage_tile<K>(B, n0, 0, sm + 16384, tid, wave);

  f32x4 acc[8][4] = {};

  #pragma unroll 1
  for (int s = 0; s < NS; ++s) {
    unsigned short* cur = sm + ((s & 1) << 15);
    unsigned short* nxt = sm + (((s + 1) & 1) << 15);
    const unsigned short* curA = cur;
    const unsigned short* curB = cur + 16384;
    const int kn = (s + 1) << 6;
    const bool pf = (s + 1 < NS);

    bf16x8 afr[8], b0[2], b1[2];

    // ---- phase 0: issue A(next) stage | vmcnt(4) | read A kk0 (8) + B n0,1 kk0 (2) | MFMA 16 ----
    if (pf) {
      stage_tile<K>(A, m0, kn, nxt, tid, wave);
      asm volatile("s_waitcnt vmcnt(4)" ::: "memory");   // tile s fully landed; 4 newest in flight
    } else {
      asm volatile("s_waitcnt vmcnt(0)" ::: "memory");   // last tile: drain
    }
    __builtin_amdgcn_s_barrier();
    __builtin_amdgcn_sched_barrier(0);
    #pragma unroll
    for (int mi = 0; mi < 8; ++mi) {
      int r = wm * 128 + mi * 16 + lrow;
      afr[mi] = *(const bf16x8*)(curA + r * 64 + ((q ^ (r & 7)) << 3));
    }
    #pragma unroll
    for (int ni = 0; ni < 2; ++ni) {
      int r = wn * 64 + ni * 16 + lrow;
      b0[ni] = *(const bf16x8*)(curB + r * 64 + ((q ^ (r & 7)) << 3));
    }
    __builtin_amdgcn_s_setprio(1);
    #pragma unroll
    for (int mi = 0; mi < 8; ++mi)
      #pragma unroll
      for (int ni = 0; ni < 2; ++ni)
        acc[mi][ni] = __builtin_amdgcn_mfma_f32_16x16x32_bf16(afr[mi], b0[ni], acc[mi][ni], 0, 0, 0);
    __builtin_amdgcn_s_setprio(0);

    // ---- phase 1: issue B(next) stage | read B n2,3 kk0 | MFMA 16 ----
    if (pf) stage_tile<K>(B, n0, kn, nxt + 16384, tid, wave);
    __builtin_amdgcn_s_barrier();
    __builtin_amdgcn_sched_barrier(0);
    #pragma unroll
    for (int ni = 0; ni < 2; ++ni) {
      int r = wn * 64 + (ni + 2) * 16 + lrow;
      b1[ni] = *(const bf16x8*)(curB + r * 64 + ((q ^ (r & 7)) << 3));
    }
    __builtin_amdgcn_s_setprio(1);
    #pragma unroll
    for (int mi = 0; mi < 8; ++mi)
      #pragma unroll
      for (int ni = 0; ni < 2; ++ni)
        acc[mi][ni + 2] = __builtin_amdgcn_mfma_f32_16x16x32_bf16(afr[mi], b1[ni], acc[mi][ni + 2], 0, 0, 0);
    __builtin_amdgcn_s_setprio(0);

    // ---- phase 2: read A kk1 (8) + B n0,1 kk1 (2) | MFMA 16 ----
    __builtin_amdgcn_s_barrier();
    __builtin_amdgcn_sched_barrier(0);
    #pragma unroll
    for (int mi = 0; mi < 8; ++mi) {
      int r = wm * 128 + mi * 16 + lrow;
      afr[mi] = *(const bf16x8*)(curA + r * 64 + (((4 + q) ^ (r & 7)) << 3));
    }
    #pragma unroll
    for (int ni = 0; ni < 2; ++ni) {
      int r = wn * 64 + ni * 16 + lrow;
      b0[ni] = *(const bf16x8*)(curB + r * 64 + (((4 + q) ^ (r & 7)) << 3));
    }
    __builtin_amdgcn_s_setprio(1);
    #pragma unroll
    for (int mi = 0; mi < 8; ++mi)
      #pragma unroll
      for (int ni = 0; ni < 2; ++ni)
        acc[mi][ni] = __builtin_amdgcn_mfma_f32_16x16x32_bf16(afr[mi], b0[ni], acc[mi][ni], 0, 0, 0);
    __builtin_amdgcn_s_setprio(0);

    // ---- phase 3: read B n2,3 kk1 | MFMA 16 | boundary barrier ----
    __builtin_amdgcn_s_barrier();
    __builtin_amdgcn_sched_barrier(0);
    #pragma unroll
    for (int ni = 0; ni < 2; ++ni) {
      int r = wn * 64 + (ni + 2) * 16 + lrow;
      b1[ni] = *(const bf16x8*)(curB + r * 64 + (((4 + q) ^ (r & 7)) << 3));
    }
    __builtin_amdgcn_s_setprio(1);
    #pragma unroll
    for (int mi = 0; mi < 8; ++mi)
      #pragma unroll
      for (int ni = 0; ni < 2; ++ni)
        acc[mi][ni + 2] = __builtin_amdgcn_mfma_f32_16x16x32_bf16(afr[mi], b1[ni], acc[mi][ni + 2], 0, 0, 0);
    __builtin_amdgcn_s_setprio(0);
    // boundary: all reads of cur complete (lgkmcnt before MFMA) before anyone
    // stages the next-next tile into this buffer.
    __builtin_amdgcn_s_barrier();
    __builtin_amdgcn_sched_barrier(0);
  }

  // ---- epilogue: C/D layout col=lane&15, row=(lane>>4)*4+reg ----
  if (OUTB) {
    unsigned short* C = (unsigned short*)Cptr;
    #pragma unroll
    for (int mi = 0; mi < 8; ++mi)
      #pragma unroll
      for (int ni = 0; ni < 4; ++ni) {
        int row = m0 + wm * 128 + mi * 16 + q * 4;
        int col = n0 + wn * 64 + ni * 16 + lrow;
        #pragma unroll
        for (int r = 0; r < 4; ++r)
          C[(size_t)(row + r) * N + col] = f2b(acc[mi][ni][r]);
      }
  } else {
    float* C = (float*)Cptr;
    #pragma unroll
    for (int mi = 0; mi < 8; ++mi)
      #pragma unroll
      for (int ni = 0; ni < 4; ++ni) {
        int row = m0 + wm * 128 + mi * 16 + q * 4;
        int col = n0 + wn * 64 + ni * 16 + lrow;
        #pragma unroll
        for (int r = 0; r < 4; ++r)
          C[(size_t)(row + r) * N + col] = acc[mi][ni][r];
      }
  }
}

// ---------------- row-wise RMS scale + gelu, in-place on bf16 sim ----------------
__global__ void norm_gelu_rows(unsigned short* __restrict__ sim) {
  const int row  = blockIdx.x * 4 + (threadIdx.x >> 6);
  const int lane = threadIdx.x & 63;
  unsigned short* p = sim + (size_t)row * 1024;
  u16x8 v0 = *(const u16x8*)&p[lane * 8];
  u16x8 v1 = *(const u16x8*)&p[512 + lane * 8];
  float f0[8], f1[8];
  float s = 0.f;
  #pragma unroll
  for (int j = 0; j < 8; ++j) { f0[j] = b2f(v0[j]); s += f0[j] * f0[j]; }
  #pragma unroll
  for (int j = 0; j < 8; ++j) { f1[j] = b2f(v1[j]); s += f1[j] * f1[j]; }
  #pragma unroll
  for (int off = 32; off >= 1; off >>= 1) s += __shfl_xor(s, off, 64);
  float scale = 32.0f * rsqrtf(fmaxf(s, 1e-20f));
  u16x8 o0, o1;
  #pragma unroll
  for (int j = 0; j < 8; ++j) o0[j] = f2b(gelu_exact(f0[j] * scale));
  #pragma unroll
  for (int j = 0; j < 8; ++j) o1[j] = f2b(gelu_exact(f1[j] * scale));
  *(u16x8*)&p[lane * 8] = o0;
  *(u16x8*)&p[512 + lane * 8] = o1;
}

extern "C" void kernel_launch(void* const* d_in, const int* in_sizes, int n_in,
                              void* d_out, int out_size, void* d_ws, size_t ws_size,
                              hipStream_t stream) {
  const float* x      = (const float*)d_in[0];
  const float* tokens = (const float*)d_in[1];
  const float* Wk1    = (const float*)d_in[2];
  const float* Wk2    = (const float*)d_in[3];
  const float* Wv1    = (const float*)d_in[4];
  const float* Wv2    = (const float*)d_in[5];

  char* ws = (char*)d_ws;
  unsigned short* xb   = (unsigned short*)(ws);                              // 64 MB
  unsigned short* keyb = (unsigned short*)(ws + (size_t)64 * 1024 * 1024);   // 4 MB
  unsigned short* valb = (unsigned short*)(ws + (size_t)68 * 1024 * 1024);   // 4 MB
  unsigned short* vtb  = (unsigned short*)(ws + (size_t)72 * 1024 * 1024);   // 4 MB
  unsigned short* simb = (unsigned short*)(ws + (size_t)76 * 1024 * 1024);   // 32 MB
  // hk/hv (256 KB each) alias the simb region: dead before gemm1 writes simb.
  float* hk = (float*)(ws + (size_t)76 * 1024 * 1024);
  float* hv = (float*)(ws + (size_t)77 * 1024 * 1024);

  hipLaunchKernelGGL(convert_x, dim3(2048), dim3(256), 0, stream, x, xb, 33554432 / 4);
  hipLaunchKernelGGL(token_h, dim3(256), dim3(256), 0, stream, tokens, Wk1, Wv1, hk, hv);
  hipLaunchKernelGGL(token_proj, dim3(8, 64, 2), dim3(256), 0, stream,
                     hk, hv, Wk2, Wv2, keyb, valb);
  hipLaunchKernelGGL(transpose_v, dim3(32, 16), dim3(256), 0, stream, valb, vtb);
  hipLaunchKernelGGL((gemm256<2048, 1024, 1>), dim3(256), dim3(512), 0, stream,
                     xb, keyb, (void*)simb);
  hipLaunchKernelGGL(norm_gelu_rows, dim3(4096), dim3(256), 0, stream, simb);
  hipLaunchKernelGGL((gemm256<1024, 2048, 0>), dim3(512), dim3(512), 0, stream,
                     simb, vtb, d_out);
}